// Round 18
// baseline (146.658 us; speedup 1.0000x reference)
//
#include <hip/hip_runtime.h>

#define NNODES 100000
#define EDGES  262144
#define NT64   1563          // ceil(NNODES/64); last tile is half (guarded)
#define GEMM_BLOCKS 256

typedef __attribute__((ext_vector_type(8))) short short8v;
typedef __attribute__((ext_vector_type(8))) unsigned short ushort8v;
typedef __attribute__((ext_vector_type(4))) float f32x4;

__device__ __forceinline__ unsigned short f2bf(float f) {
  unsigned u = __builtin_bit_cast(unsigned, f);
  u += 0x7fffu + ((u >> 16) & 1u);
  return (unsigned short)(u >> 16);
}
__device__ __forceinline__ float bf2f(unsigned short u) {
  return __builtin_bit_cast(float, (unsigned)u << 16);
}
// HW packed f32->bf16 (RNE), two values -> one dword [lo|hi]
__device__ __forceinline__ unsigned cvt_pk(float lo, float hi) {
  unsigned r;
  asm volatile("v_cvt_pk_bf16_f32 %0, %1, %2" : "=v"(r) : "v"(lo), "v"(hi));
  return r;
}
// async global->LDS, 16 bytes per lane (width-16 proven: m97)
__device__ __forceinline__ void gload16(const float* g, float* l) {
  __builtin_amdgcn_global_load_lds(
      (const __attribute__((address_space(1))) unsigned int*)g,
      (__attribute__((address_space(3))) unsigned int*)l, 16, 0, 0);
}

// ---------------------------------------------------------------------------
// Kernel 0: repack W1 (fp32 [256][512]) -> Wc (bf16 [512][256], k-major).
// (proven r1/r2/r9/r10/r13/r14)
// ---------------------------------------------------------------------------
__global__ __launch_bounds__(256) void prep_wc(const float* __restrict__ W1,
                                               unsigned short* __restrict__ Wc) {
  int idx = blockIdx.x * 256 + threadIdx.x;   // 0 .. 512*256-1
  int j = idx >> 8;
  int k = idx & 255;
  int jj = j & 255;
  int kk = (k < 128) ? k : (k + 128);
  if (j >= 256) kk += 128;
  Wc[idx] = f2bf(W1[jj * 512 + kk]);
}

// ---------------------------------------------------------------------------
// GEMM v18: 512 thr = 8 waves x 64 j (r10/r14 mapping), 64-node tiles, A
// staged RAW FP32 via global_load_lds (no staging VGPRs, async) into a
// LINEAR LDS [2][64][256] f32 (128 KB) with XOR-swizzled SOURCE chunks
// (cc = c ^ (r&7), 16B granularity; same XOR on read -> conflict-free).
// fp32->bf16 conversion happens at LDS-read time (cvt_pk, VALU idle).
// Live-through = acc[4][4]=64 + addressing -> bfrag[8][4] remat flows in the
// slack exactly as proven in r10/r14.  Remat per node HALVES; barriers halve.
// Compute mapping == r15 (correctness-proven).  Tail clamp/pred == r13.
//
// P[n][j] = sum_k h[n][k]*Wc[j][k] + (j<256 ? b1[j] : 0)
// Swapped-operand MFMA: C row = j, col = node -> packed uint2 stores.
// ---------------------------------------------------------------------------
__global__ __launch_bounds__(512)
void gemm_proj18(const float* __restrict__ ne,
                 const float* __restrict__ mem,
                 const unsigned short* __restrict__ Wc,
                 const float* __restrict__ b1,
                 unsigned short* __restrict__ P) {
  __shared__ __align__(16) float As[2][64][256];   // raw fp32, linear, 128 KB
  const int tid  = threadIdx.x;
  const int bid  = blockIdx.x;
  const int wid  = tid >> 6;          // 0..7
  const int lane = tid & 63;
  const int lr   = lane & 15;
  const int kq   = (lane >> 4) * 8;   // 0,8,16,24
  const int cb   = wid * 64;          // this wave's j base
  const int sxor = lr & 7;            // read-side chunk XOR (row&7; rows lr+16h share it)

  // ---- B panel (MFMA A-operand): plain 16B loads from Wc -> remat-able ----
  ushort8v bfrag[8][4];
#pragma unroll
  for (int ks = 0; ks < 8; ++ks)
#pragma unroll
    for (int jt = 0; jt < 4; ++jt)
      bfrag[ks][jt] = *(const ushort8v*)(Wc + (size_t)(cb + jt * 16 + lr) * 256 + ks * 32 + kq);

  const int nt = (NT64 - bid + GEMM_BLOCKS - 1) / GEMM_BLOCKS;  // 7 or 6

  // ---- stage tile 0 via global_load_lds: 4096 chunks of 16B / 512 thr ----
#pragma unroll
  for (int i = 0; i < 8; ++i) {
    int q = tid + i * 512;            // 0..4095
    int r = q >> 6;                   // row 0..63
    int c = q & 63;                   // chunk-in-row
    int cc = c ^ (r & 7);             // swizzled SOURCE chunk (involution)
    int col = cc * 4;                 // float col 0..252
    int node = bid * 64 + r;          // <= 16383, in range
    const float* src = (col < 128) ? ne + (size_t)node * 128 + col
                                   : mem + (size_t)node * 128 + (col - 128);
    gload16(src, &As[0][0][0] + (size_t)q * 4);
  }
  __syncthreads();

  for (int it = 0; it < nt; ++it) {
    const int tile = bid + it * GEMM_BLOCKS;
    const int buf  = it & 1;
    const bool more = (it + 1 < nt);

    // issue next tile's async gload EARLY (hides under MFMA; barrier drains)
    if (more) {
      const int ntile = tile + GEMM_BLOCKS;
      float* dst = &As[buf ^ 1][0][0];
#pragma unroll
      for (int i = 0; i < 8; ++i) {
        int q = tid + i * 512;
        int r = q >> 6;
        int c = q & 63;
        int cc = c ^ (r & 7);
        int col = cc * 4;
        int node = ntile * 64 + r;
        if (node > NNODES - 1) node = NNODES - 1;   // clamp (load-safe)
        const float* src = (col < 128) ? ne + (size_t)node * 128 + col
                                       : mem + (size_t)node * 128 + (col - 128);
        gload16(src, dst + (size_t)q * 4);
      }
    }

    // ---- MFMA over K=256; A read from swizzled fp32 LDS + cvt_pk ----
    const float* tb = &As[buf][0][0];
    f32x4 acc[4][4] = {};
#pragma unroll
    for (int ks = 0; ks < 8; ++ks) {
      const int c0 = ks * 8 + (kq >> 2);          // even chunk index
      ushort8v av[4];
#pragma unroll
      for (int h = 0; h < 4; ++h) {
        const int row = lr + 16 * h;
        const float* rp = tb + row * 256;
        float4 lo = *(const float4*)(rp + ((c0 ^ sxor) << 2));
        float4 hi = *(const float4*)(rp + (((c0 + 1) ^ sxor) << 2));
        uint4 u { cvt_pk(lo.x, lo.y), cvt_pk(lo.z, lo.w),
                  cvt_pk(hi.x, hi.y), cvt_pk(hi.z, hi.w) };
        av[h] = __builtin_bit_cast(ushort8v, u);
      }
#pragma unroll
      for (int jt = 0; jt < 4; ++jt) {
        acc[jt][0] = __builtin_amdgcn_mfma_f32_16x16x32_bf16((short8v)bfrag[ks][jt], (short8v)av[0], acc[jt][0], 0, 0, 0);
        acc[jt][1] = __builtin_amdgcn_mfma_f32_16x16x32_bf16((short8v)bfrag[ks][jt], (short8v)av[1], acc[jt][1], 0, 0, 0);
        acc[jt][2] = __builtin_amdgcn_mfma_f32_16x16x32_bf16((short8v)bfrag[ks][jt], (short8v)av[2], acc[jt][2], 0, 0, 0);
        acc[jt][3] = __builtin_amdgcn_mfma_f32_16x16x32_bf16((short8v)bfrag[ks][jt], (short8v)av[3], acc[jt][3], 0, 0, 0);
      }
    }

    // ---- store: C row = j (4 consecutive per lane -> one 8B packed store) ----
#pragma unroll
    for (int jt = 0; jt < 4; ++jt) {
      const int jq = cb + jt * 16 + (lane >> 4) * 4;     // lane's 4-j base
      float4 bv = (cb < 256) ? *(const float4*)(b1 + jq) : float4{0.f, 0.f, 0.f, 0.f};
#pragma unroll
      for (int h = 0; h < 4; ++h) {
        int node = tile * 64 + h * 16 + lr;
        if (node < NNODES) {
          f32x4 v = acc[jt][h];
          uint2 pk { cvt_pk(v[0] + bv.x, v[1] + bv.y),
                     cvt_pk(v[2] + bv.z, v[3] + bv.w) };
          *(uint2*)(P + (size_t)node * 512 + jq) = pk;
        }
      }
    }

    __syncthreads();   // drains async gloads (compiler emits vmcnt(0) here)
  }
}

// ---------------------------------------------------------------------------
// Edge score v4 (proven r13/r14): 4 edges/wave, 16 lanes/edge, each lane
// reads 16 bf16 at element offset l4*16 from each of the two P halves.
// out[e] = relu(P[src][0:256] + P[dst][256:512]) . W2 + b2
// ---------------------------------------------------------------------------
__global__ __launch_bounds__(256) void edge_score4(const int* __restrict__ src,
                                                   const int* __restrict__ dst,
                                                   const unsigned short* __restrict__ P,
                                                   const float* __restrict__ W2,
                                                   const float* __restrict__ b2,
                                                   float* __restrict__ out) {
  const int t  = threadIdx.x;
  const int l4 = t & 15;                     // lane within 16-group
  const int e  = blockIdx.x * 16 + (t >> 4);

  float4 w0  = *(const float4*)(W2 + l4 * 16);
  float4 w1  = *(const float4*)(W2 + l4 * 16 + 4);
  float4 w2v = *(const float4*)(W2 + l4 * 16 + 8);
  float4 w3  = *(const float4*)(W2 + l4 * 16 + 12);
  const float b2c = b2[0];

  const int s = src[e];
  const int d = dst[e];

  const unsigned short* ps = P + (size_t)s * 512 + l4 * 16;
  const unsigned short* pd = P + (size_t)d * 512 + 256 + l4 * 16;
  ushort8v a0 = *(const ushort8v*)(ps);
  ushort8v a1 = *(const ushort8v*)(ps + 8);
  ushort8v c0 = *(const ushort8v*)(pd);
  ushort8v c1 = *(const ushort8v*)(pd + 8);

  float partial = 0.f;
#pragma unroll
  for (int i = 0; i < 4; ++i) {
    float h = bf2f(a0[i]) + bf2f(c0[i]); h = h > 0.f ? h : 0.f;
    partial += h * (&w0.x)[i];
  }
#pragma unroll
  for (int i = 0; i < 4; ++i) {
    float h = bf2f(a0[i + 4]) + bf2f(c0[i + 4]); h = h > 0.f ? h : 0.f;
    partial += h * (&w1.x)[i];
  }
#pragma unroll
  for (int i = 0; i < 4; ++i) {
    float h = bf2f(a1[i]) + bf2f(c1[i]); h = h > 0.f ? h : 0.f;
    partial += h * (&w2v.x)[i];
  }
#pragma unroll
  for (int i = 0; i < 4; ++i) {
    float h = bf2f(a1[i + 4]) + bf2f(c1[i + 4]); h = h > 0.f ? h : 0.f;
    partial += h * (&w3.x)[i];
  }

#pragma unroll
  for (int off = 8; off; off >>= 1) partial += __shfl_xor(partial, off, 64);

  if (l4 == 0) out[e] = partial + b2c;
}

// ---------------------------------------------------------------------------
// Fallback (only if ws_size too small): direct per-edge MLP, 8 edges / block.
// ---------------------------------------------------------------------------
__global__ __launch_bounds__(256) void fallback_edge(const int* __restrict__ src,
                                                     const int* __restrict__ dst,
                                                     const float* __restrict__ ne,
                                                     const float* __restrict__ mem,
                                                     const float* __restrict__ W1,
                                                     const float* __restrict__ b1,
                                                     const float* __restrict__ W2,
                                                     const float* __restrict__ b2,
                                                     float* __restrict__ out) {
  __shared__ float hs[8][512];
  __shared__ float red[8][4];
  const int tid = threadIdx.x;
  const int e0  = blockIdx.x * 8;

  for (int idx = tid; idx < 8 * 512; idx += 256) {
    int e8 = idx >> 9, k = idx & 511;
    int e = e0 + e8;
    int s = src[e], d = dst[e];
    float v;
    if (k < 128)      v = ne[(size_t)s * 128 + k];
    else if (k < 256) v = ne[(size_t)d * 128 + k - 128];
    else if (k < 384) v = mem[(size_t)s * 128 + k - 256];
    else              v = mem[(size_t)d * 128 + k - 384];
    hs[e8][k] = v;
  }
  __syncthreads();

  const int j = tid;
  float acc[8] = {0, 0, 0, 0, 0, 0, 0, 0};
  const float* w1r = W1 + (size_t)j * 512;
  for (int k = 0; k < 512; k += 4) {
    float4 w = *(const float4*)(w1r + k);
#pragma unroll
    for (int e8 = 0; e8 < 8; ++e8)
      acc[e8] += hs[e8][k] * w.x + hs[e8][k + 1] * w.y + hs[e8][k + 2] * w.z + hs[e8][k + 3] * w.w;
  }
  const float bj = b1[j], wj = W2[j];
#pragma unroll
  for (int e8 = 0; e8 < 8; ++e8) {
    float h = acc[e8] + bj;
    h = h > 0.f ? h : 0.f;
    acc[e8] = h * wj;
  }
  const int lane = tid & 63, wid = tid >> 6;
#pragma unroll
  for (int e8 = 0; e8 < 8; ++e8) {
    float p = acc[e8];
#pragma unroll
    for (int off = 32; off; off >>= 1) p += __shfl_xor(p, off, 64);
    if (lane == 0) red[e8][wid] = p;
  }
  __syncthreads();
  if (tid < 8) out[e0 + tid] = red[tid][0] + red[tid][1] + red[tid][2] + red[tid][3] + b2[0];
}

// ---------------------------------------------------------------------------
extern "C" void kernel_launch(void* const* d_in, const int* in_sizes, int n_in,
                              void* d_out, int out_size, void* d_ws, size_t ws_size,
                              hipStream_t stream) {
  const int*   src      = (const int*)d_in[0];
  const int*   dst      = (const int*)d_in[1];
  const float* node_emb = (const float*)d_in[4];
  const float* memv     = (const float*)d_in[5];
  const float* W1       = (const float*)d_in[10];
  const float* b1       = (const float*)d_in[11];
  const float* W2       = (const float*)d_in[12];
  const float* b2       = (const float*)d_in[13];
  float*       out      = (float*)d_out;

  const size_t P_BYTES  = (size_t)NNODES * 512 * 2;   // 102,400,000
  const size_t WC_BYTES = (size_t)512 * 256 * 2;      //     262,144

  if (ws_size >= P_BYTES + WC_BYTES) {
    unsigned short* P  = (unsigned short*)d_ws;
    unsigned short* Wc = (unsigned short*)((char*)d_ws + P_BYTES);
    prep_wc<<<512, 256, 0, stream>>>(W1, Wc);
    gemm_proj18<<<GEMM_BLOCKS, 512, 0, stream>>>(node_emb, memv, Wc, b1, P);
    edge_score4<<<EDGES / 16, 256, 0, stream>>>(src, dst, P, W2, b2, out);
  } else {
    fallback_edge<<<EDGES / 8, 256, 0, stream>>>(src, dst, node_emb, memv, W1, b1, W2, b2, out);
  }
}

// Round 19
// 89.462 us; speedup vs baseline: 1.6393x; 1.6393x over previous
//
#include <hip/hip_runtime.h>

#define NNODES 100000
#define EDGES  262144
#define NTILES 3125          // NNODES / 32
#define GEMM_BLOCKS 256

typedef __attribute__((ext_vector_type(8))) short short8v;
typedef __attribute__((ext_vector_type(8))) unsigned short ushort8v;
typedef __attribute__((ext_vector_type(4))) float f32x4;

__device__ __forceinline__ unsigned short f2bf(float f) {
  unsigned u = __builtin_bit_cast(unsigned, f);
  u += 0x7fffu + ((u >> 16) & 1u);
  return (unsigned short)(u >> 16);
}
__device__ __forceinline__ float bf2f(unsigned short u) {
  return __builtin_bit_cast(float, (unsigned)u << 16);
}
// HW packed f32->bf16 (RNE), two values -> one dword [lo|hi]
__device__ __forceinline__ unsigned cvt_pk(float lo, float hi) {
  unsigned r;
  asm volatile("v_cvt_pk_bf16_f32 %0, %1, %2" : "=v"(r) : "v"(lo), "v"(hi));
  return r;
}

// ---------------------------------------------------------------------------
// Kernel 0: repack W1 (fp32 [256][512]) -> Wc2 in WAVE-FRAGMENT order:
// Wc2[wid][ks][jt][lane][8] ushorts (256 KB total).  A wave's bfrag[ks][jt]
// remat load becomes ONE contiguous 1 KB wave-load (64 lanes x adjacent 16B)
// instead of r14's 16B-per-lane at 512B stride (16 cache lines / load).
// Element: j = wid*64 + jt*16 + (lane&15); k = ks*32 + (lane>>4)*8 + m;
// value  = W1[j&255][k + (k>=128?128:0) + (j>=256?128:0)]  (same math as r14).
// ---------------------------------------------------------------------------
__global__ __launch_bounds__(256) void prep_wc2(const float* __restrict__ W1,
                                                unsigned short* __restrict__ Wc2) {
  int idx  = blockIdx.x * 256 + threadIdx.x;   // 0 .. 131071
  int m    = idx & 7;
  int lane = (idx >> 3) & 63;
  int jt   = (idx >> 9) & 3;
  int ks   = (idx >> 11) & 7;
  int wid  = idx >> 14;                        // 0..7
  int j = wid * 64 + jt * 16 + (lane & 15);
  int k = ks * 32 + (lane >> 4) * 8 + m;
  int jj = j & 255;
  int kk = k + (k >= 128 ? 128 : 0) + (j >= 256 ? 128 : 0);
  Wc2[idx] = f2bf(W1[jj * 512 + kk]);
}

// ---------------------------------------------------------------------------
// GEMM = r14's EXACT kernel except bfrag loads read the repacked Wc2
// (coalesced 1KB wave-loads; same remat-friendly plain-load form).
// 512 thr = 8 waves; wave owns 64 j; 32-node tiles; LDS [2][32][272].
//
// P[n][j] = sum_k h[n][k]*Wc[j][k] + (j<256 ? b1[j] : 0)
// Swapped-operand MFMA: C row = j, col = node -> packed uint2 stores.
// ---------------------------------------------------------------------------
__global__ __launch_bounds__(512)
void gemm_proj19(const float* __restrict__ ne,
                 const float* __restrict__ mem,
                 const unsigned short* __restrict__ Wc2,
                 const float* __restrict__ b1,
                 unsigned short* __restrict__ P) {
  __shared__ __align__(16) unsigned short As[2][32][272];  // stride 272: 0 conflicts
  const int tid  = threadIdx.x;
  const int bid  = blockIdx.x;
  const int wid  = tid >> 6;          // 0..7
  const int lane = tid & 63;
  const int lr   = lane & 15;
  const int kq   = (lane >> 4) * 8;   // 0,8,16,24
  const int cb   = wid * 64;          // this wave's j base

  // ---- B panel: coalesced 16B/lane loads from Wc2 -> remat-able ----
  const unsigned short* wbase = Wc2 + ((size_t)wid * 8 * 4 * 64 + (size_t)lane) * 8;
  ushort8v bfrag[8][4];
#pragma unroll
  for (int ks = 0; ks < 8; ++ks)
#pragma unroll
    for (int jt = 0; jt < 4; ++jt)
      bfrag[ks][jt] = *(const ushort8v*)(wbase + ((size_t)ks * 4 + jt) * 64 * 8);

  const int nt = (NTILES - bid + GEMM_BLOCKS - 1) / GEMM_BLOCKS;

  // ---- stage tile 0 (2048 float4-chunks / 512 thr -> g[4]) ----
  float4 g[4];
#pragma unroll
  for (int i = 0; i < 4; ++i) {
    int q = tid + i * 512;            // 0..2047
    int row = q >> 6;
    int k0  = (q & 63) * 4;
    int node = bid * 32 + row;
    g[i] = *(const float4*)((k0 < 128) ? ne + (size_t)node * 128 + k0
                                       : mem + (size_t)node * 128 + (k0 - 128));
  }
#pragma unroll
  for (int i = 0; i < 4; ++i) {
    int q = tid + i * 512;
    int row = q >> 6;
    int k0  = (q & 63) * 4;
    uint2 pk { cvt_pk(g[i].x, g[i].y), cvt_pk(g[i].z, g[i].w) };
    *(uint2*)&As[0][row][k0] = pk;
  }
  __syncthreads();

  for (int it = 0; it < nt; ++it) {
    const int tile = bid + it * GEMM_BLOCKS;
    const int buf  = it & 1;
    const bool more = (it + 1 < nt);

    // issue next tile's global loads EARLY (hide HBM latency under MFMA)
    if (more) {
      const int ntile = bid + (it + 1) * GEMM_BLOCKS;
#pragma unroll
      for (int i = 0; i < 4; ++i) {
        int q = tid + i * 512;
        int row = q >> 6;
        int k0  = (q & 63) * 4;
        int node = ntile * 32 + row;
        g[i] = *(const float4*)((k0 < 128) ? ne + (size_t)node * 128 + k0
                                           : mem + (size_t)node * 128 + (k0 - 128));
      }
    }

    // ---- MFMA over K=256 (swapped: A=W-frag, B=node-frag), fully unrolled ----
    f32x4 acc[4][2] = {};
#pragma unroll
    for (int ks = 0; ks < 8; ++ks) {
      const int kk = ks * 32 + kq;
      ushort8v a0 = *(const ushort8v*)&As[buf][lr][kk];        // nodes 0..15
      ushort8v a1 = *(const ushort8v*)&As[buf][lr + 16][kk];   // nodes 16..31
#pragma unroll
      for (int jt = 0; jt < 4; ++jt) {
        acc[jt][0] = __builtin_amdgcn_mfma_f32_16x16x32_bf16((short8v)bfrag[ks][jt], (short8v)a0, acc[jt][0], 0, 0, 0);
        acc[jt][1] = __builtin_amdgcn_mfma_f32_16x16x32_bf16((short8v)bfrag[ks][jt], (short8v)a1, acc[jt][1], 0, 0, 0);
      }
    }

    // ---- store: C row = j (4 consecutive per lane -> one 8B packed store) ----
#pragma unroll
    for (int jt = 0; jt < 4; ++jt) {
      const int jq = cb + jt * 16 + (lane >> 4) * 4;     // lane's 4-j base
      float4 bv = (cb < 256) ? *(const float4*)(b1 + jq) : float4{0.f, 0.f, 0.f, 0.f};
#pragma unroll
      for (int h = 0; h < 2; ++h) {
        int node = tile * 32 + h * 16 + lr;
        f32x4 v = acc[jt][h];
        uint2 pk { cvt_pk(v[0] + bv.x, v[1] + bv.y),
                   cvt_pk(v[2] + bv.z, v[3] + bv.w) };
        *(uint2*)(P + (size_t)node * 512 + jq) = pk;
      }
    }

    // write next tile into the OTHER buffer; one barrier per tile
    if (more) {
#pragma unroll
      for (int i = 0; i < 4; ++i) {
        int q = tid + i * 512;
        int row = q >> 6;
        int k0  = (q & 63) * 4;
        uint2 pk { cvt_pk(g[i].x, g[i].y), cvt_pk(g[i].z, g[i].w) };
        *(uint2*)&As[buf ^ 1][row][k0] = pk;
      }
    }
    __syncthreads();
  }
}

// ---------------------------------------------------------------------------
// Edge score v4 (proven r13/r14): 4 edges/wave, 16 lanes/edge, each lane
// reads 16 bf16 at element offset l4*16 from each of the two P halves.
// out[e] = relu(P[src][0:256] + P[dst][256:512]) . W2 + b2
// ---------------------------------------------------------------------------
__global__ __launch_bounds__(256) void edge_score4(const int* __restrict__ src,
                                                   const int* __restrict__ dst,
                                                   const unsigned short* __restrict__ P,
                                                   const float* __restrict__ W2,
                                                   const float* __restrict__ b2,
                                                   float* __restrict__ out) {
  const int t  = threadIdx.x;
  const int l4 = t & 15;                     // lane within 16-group
  const int e  = blockIdx.x * 16 + (t >> 4);

  float4 w0  = *(const float4*)(W2 + l4 * 16);
  float4 w1  = *(const float4*)(W2 + l4 * 16 + 4);
  float4 w2v = *(const float4*)(W2 + l4 * 16 + 8);
  float4 w3  = *(const float4*)(W2 + l4 * 16 + 12);
  const float b2c = b2[0];

  const int s = src[e];
  const int d = dst[e];

  const unsigned short* ps = P + (size_t)s * 512 + l4 * 16;
  const unsigned short* pd = P + (size_t)d * 512 + 256 + l4 * 16;
  ushort8v a0 = *(const ushort8v*)(ps);
  ushort8v a1 = *(const ushort8v*)(ps + 8);
  ushort8v c0 = *(const ushort8v*)(pd);
  ushort8v c1 = *(const ushort8v*)(pd + 8);

  float partial = 0.f;
#pragma unroll
  for (int i = 0; i < 4; ++i) {
    float h = bf2f(a0[i]) + bf2f(c0[i]); h = h > 0.f ? h : 0.f;
    partial += h * (&w0.x)[i];
  }
#pragma unroll
  for (int i = 0; i < 4; ++i) {
    float h = bf2f(a0[i + 4]) + bf2f(c0[i + 4]); h = h > 0.f ? h : 0.f;
    partial += h * (&w1.x)[i];
  }
#pragma unroll
  for (int i = 0; i < 4; ++i) {
    float h = bf2f(a1[i]) + bf2f(c1[i]); h = h > 0.f ? h : 0.f;
    partial += h * (&w2v.x)[i];
  }
#pragma unroll
  for (int i = 0; i < 4; ++i) {
    float h = bf2f(a1[i + 4]) + bf2f(c1[i + 4]); h = h > 0.f ? h : 0.f;
    partial += h * (&w3.x)[i];
  }

#pragma unroll
  for (int off = 8; off; off >>= 1) partial += __shfl_xor(partial, off, 64);

  if (l4 == 0) out[e] = partial + b2c;
}

// ---------------------------------------------------------------------------
// Fallback (only if ws_size too small): direct per-edge MLP, 8 edges / block.
// ---------------------------------------------------------------------------
__global__ __launch_bounds__(256) void fallback_edge(const int* __restrict__ src,
                                                     const int* __restrict__ dst,
                                                     const float* __restrict__ ne,
                                                     const float* __restrict__ mem,
                                                     const float* __restrict__ W1,
                                                     const float* __restrict__ b1,
                                                     const float* __restrict__ W2,
                                                     const float* __restrict__ b2,
                                                     float* __restrict__ out) {
  __shared__ float hs[8][512];
  __shared__ float red[8][4];
  const int tid = threadIdx.x;
  const int e0  = blockIdx.x * 8;

  for (int idx = tid; idx < 8 * 512; idx += 256) {
    int e8 = idx >> 9, k = idx & 511;
    int e = e0 + e8;
    int s = src[e], d = dst[e];
    float v;
    if (k < 128)      v = ne[(size_t)s * 128 + k];
    else if (k < 256) v = ne[(size_t)d * 128 + k - 128];
    else if (k < 384) v = mem[(size_t)s * 128 + k - 256];
    else              v = mem[(size_t)d * 128 + k - 384];
    hs[e8][k] = v;
  }
  __syncthreads();

  const int j = tid;
  float acc[8] = {0, 0, 0, 0, 0, 0, 0, 0};
  const float* w1r = W1 + (size_t)j * 512;
  for (int k = 0; k < 512; k += 4) {
    float4 w = *(const float4*)(w1r + k);
#pragma unroll
    for (int e8 = 0; e8 < 8; ++e8)
      acc[e8] += hs[e8][k] * w.x + hs[e8][k + 1] * w.y + hs[e8][k + 2] * w.z + hs[e8][k + 3] * w.w;
  }
  const float bj = b1[j], wj = W2[j];
#pragma unroll
  for (int e8 = 0; e8 < 8; ++e8) {
    float h = acc[e8] + bj;
    h = h > 0.f ? h : 0.f;
    acc[e8] = h * wj;
  }
  const int lane = tid & 63, wid = tid >> 6;
#pragma unroll
  for (int e8 = 0; e8 < 8; ++e8) {
    float p = acc[e8];
#pragma unroll
    for (int off = 32; off; off >>= 1) p += __shfl_xor(p, off, 64);
    if (lane == 0) red[e8][wid] = p;
  }
  __syncthreads();
  if (tid < 8) out[e0 + tid] = red[tid][0] + red[tid][1] + red[tid][2] + red[tid][3] + b2[0];
}

// ---------------------------------------------------------------------------
extern "C" void kernel_launch(void* const* d_in, const int* in_sizes, int n_in,
                              void* d_out, int out_size, void* d_ws, size_t ws_size,
                              hipStream_t stream) {
  const int*   src      = (const int*)d_in[0];
  const int*   dst      = (const int*)d_in[1];
  const float* node_emb = (const float*)d_in[4];
  const float* memv     = (const float*)d_in[5];
  const float* W1       = (const float*)d_in[10];
  const float* b1       = (const float*)d_in[11];
  const float* W2       = (const float*)d_in[12];
  const float* b2       = (const float*)d_in[13];
  float*       out      = (float*)d_out;

  const size_t P_BYTES  = (size_t)NNODES * 512 * 2;   // 102,400,000
  const size_t WC_BYTES = (size_t)512 * 256 * 2;      //     262,144

  if (ws_size >= P_BYTES + WC_BYTES) {
    unsigned short* P   = (unsigned short*)d_ws;
    unsigned short* Wc2 = (unsigned short*)((char*)d_ws + P_BYTES);
    prep_wc2<<<512, 256, 0, stream>>>(W1, Wc2);
    gemm_proj19<<<GEMM_BLOCKS, 512, 0, stream>>>(node_emb, memv, Wc2, b1, P);
    edge_score4<<<EDGES / 16, 256, 0, stream>>>(src, dst, P, W2, b2, out);
  } else {
    fallback_edge<<<EDGES / 8, 256, 0, stream>>>(src, dst, node_emb, memv, W1, b1, W2, b2, out);
  }
}